// Round 4
// baseline (196.156 us; speedup 1.0000x reference)
//
#include <hip/hip_runtime.h>
#include <hip/hip_bf16.h>
#include <math.h>

#define BATCH 8
#define SQ 2048
#define SK 2048
#define DD 512
#define DV 512
#define RP 40   // LDS row pitch in shorts (80 B).

typedef short bf16x8_t __attribute__((ext_vector_type(8)));
typedef float f32x4_t __attribute__((ext_vector_type(4)));

// packed RTNE fp32x2 -> bf16x2 (v_cvt_pk_bf16_f32)
__device__ __forceinline__ unsigned int pk_bf16(float a, float b) {
    __hip_bfloat162 h = __float22bfloat162_rn(float2{a, b});
    unsigned int u;
    __builtin_memcpy(&u, &h, 4);
    return u;
}
__device__ __forceinline__ float from_hi(unsigned int u) {
    return __builtin_bit_cast(float, u);
}

// ---------------------------------------------------------------------------
// Kernel 1: fp32 partials of M^T = V^T K (un-scaled), t-split by 4.
// A-frags from V, B-frags from K -> accumulator tile is [v][d] directly.
// Mpart: [ts(4)][b(8)][v(512)][d(512)] fp32 == 32 MB, lives in d_out.
// Round-4 change (ISOLATED from the round-1 failure): vectorized staging only.
//  - float4 global loads: (tq,dq) ownership -> 8 dwordx4/thread/step (was 32
//    scalar dword). Same (t,t+1) pk_bf16 pairing -> bit-identical numerics.
//  - ds_write_b64 (16/thread/step, was 32 b32) with byte-XOR swizzle
//    boff ^= ((row>>3)&3)<<4 on BOTH write and frag-read sides; write-side
//    spread = 16 bank-pairs (wave64-b64 minimum), read spread unchanged.
// Schedule is the round-0 known-good form: plain __syncthreads, distance-1
// register prefetch issued after the first barrier. No sched_barrier (m141),
// no setprio (m190), no raw barriers.
// 3-term split MFMA: Vh*Kh + Vh*Kl + Vl*Kh.
// ---------------------------------------------------------------------------
__global__ __launch_bounds__(256) void ktv_mfma(const float* __restrict__ Kp,
                                                const float* __restrict__ Vp,
                                                float* __restrict__ Mpart) {
    const int b  = blockIdx.z & 7;
    const int ts = blockIdx.z >> 3;
    const int d0 = blockIdx.x * 128;
    const int v0 = blockIdx.y * 128;
    const float* Kb = Kp + (size_t)b * SK * DD;
    const float* Vb = Vp + (size_t)b * SK * DV;

    __shared__ __align__(16) unsigned short Kh[128 * RP], Kl[128 * RP],
                                            Vh[128 * RP], Vl[128 * RP];

    const int tid  = threadIdx.x;
    const int lane = tid & 63;
    const int w    = tid >> 6;
    const int wv   = (w & 1) * 64;    // A-side: v rows
    const int wd   = (w >> 1) * 64;   // B-side: d rows
    const int tq   = tid >> 5;   // 0..7  t-quad (4 consecutive t)
    const int dq   = tid & 31;   // 0..31 d-quad (4 consecutive d)

    f32x4_t acc[4][4];
#pragma unroll
    for (int i = 0; i < 4; ++i)
#pragma unroll
        for (int j = 0; j < 4; ++j) acc[i][j] = (f32x4_t){0.f, 0.f, 0.f, 0.f};

    const int tb = ts * 512;
    // write swizzle: row = 4*dq+dd -> (row>>3)&3 == (dq>>1)&3 for all dd in 0..3
    const int swz = ((dq >> 1) & 3) << 4;

    // prefetch registers: 4 K rows + 4 V rows, one float4 each
    f32x4_t kr[4], vr[4];
    auto load_tile = [&](int t0l) {
#pragma unroll
        for (int r = 0; r < 4; ++r) {
            const size_t gr = (size_t)(tb + t0l + 4 * tq + r);
            kr[r] = *(const f32x4_t*)&Kb[gr * DD + d0 + 4 * dq];
            vr[r] = *(const f32x4_t*)&Vb[gr * DV + v0 + 4 * dq];
        }
    };

    load_tile(0);
    for (int t0 = 0; t0 < 512; t0 += 32) {
        // ---- cvt + LDS store from prefetched regs ----
#pragma unroll
        for (int dd = 0; dd < 4; ++dd) {
            const int boff = ((4 * dq + dd) * (2 * RP) + 8 * tq) ^ swz;
            {
                const unsigned int h0 = pk_bf16(kr[0][dd], kr[1][dd]);
                const unsigned int h1 = pk_bf16(kr[2][dd], kr[3][dd]);
                const float r0 = kr[0][dd] - from_hi(h0 << 16);
                const float r1 = kr[1][dd] - from_hi(h0 & 0xFFFF0000u);
                const float r2 = kr[2][dd] - from_hi(h1 << 16);
                const float r3 = kr[3][dd] - from_hi(h1 & 0xFFFF0000u);
                *(uint2*)((char*)Kh + boff) = make_uint2(h0, h1);
                *(uint2*)((char*)Kl + boff) = make_uint2(pk_bf16(r0, r1), pk_bf16(r2, r3));
            }
            {
                const unsigned int h0 = pk_bf16(vr[0][dd], vr[1][dd]);
                const unsigned int h1 = pk_bf16(vr[2][dd], vr[3][dd]);
                const float r0 = vr[0][dd] - from_hi(h0 << 16);
                const float r1 = vr[1][dd] - from_hi(h0 & 0xFFFF0000u);
                const float r2 = vr[2][dd] - from_hi(h1 << 16);
                const float r3 = vr[3][dd] - from_hi(h1 & 0xFFFF0000u);
                *(uint2*)((char*)Vh + boff) = make_uint2(h0, h1);
                *(uint2*)((char*)Vl + boff) = make_uint2(pk_bf16(r0, r1), pk_bf16(r2, r3));
            }
        }
        __syncthreads();

        // issue next tile's loads now -- they overlap the MFMA block below
        if (t0 + 32 < 512) load_tile(t0 + 32);

        // ---- MFMA (A = V rows, B = K rows) ----
        const int kq = lane >> 4;
        const int mr = lane & 15;
        bf16x8_t ah[4], al_[4];
#pragma unroll
        for (int tm = 0; tm < 4; ++tm) {
            const int row  = wv + tm * 16 + mr;
            const int boff = (row * (2 * RP) + kq * 16) ^ (((row >> 3) & 3) << 4);
            ah[tm]  = *(const bf16x8_t*)((const char*)Vh + boff);
            al_[tm] = *(const bf16x8_t*)((const char*)Vl + boff);
        }
#pragma unroll
        for (int tn = 0; tn < 4; ++tn) {
            const int row  = wd + tn * 16 + mr;
            const int boff = (row * (2 * RP) + kq * 16) ^ (((row >> 3) & 3) << 4);
            const bf16x8_t bh = *(const bf16x8_t*)((const char*)Kh + boff);
            const bf16x8_t bl = *(const bf16x8_t*)((const char*)Kl + boff);
#pragma unroll
            for (int tm = 0; tm < 4; ++tm) {
                acc[tm][tn] = __builtin_amdgcn_mfma_f32_16x16x32_bf16(ah[tm], bh, acc[tm][tn], 0, 0, 0);
                acc[tm][tn] = __builtin_amdgcn_mfma_f32_16x16x32_bf16(ah[tm], bl, acc[tm][tn], 0, 0, 0);
                acc[tm][tn] = __builtin_amdgcn_mfma_f32_16x16x32_bf16(al_[tm], bh, acc[tm][tn], 0, 0, 0);
            }
        }
        __syncthreads();
    }

    // epilogue: fp32 partial, [v][d] layout (C/D: col=lane&15, row=quad*4+reg)
    float* Mp = Mpart + (size_t)(ts * 8 + b) * DV * DD;
    const int quad = lane >> 4;
    const int col  = lane & 15;
#pragma unroll
    for (int tm = 0; tm < 4; ++tm)
#pragma unroll
        for (int tn = 0; tn < 4; ++tn)
#pragma unroll
            for (int r = 0; r < 4; ++r) {
                const int v = v0 + wv + tm * 16 + quad * 4 + r;  // A-side row
                const int d = d0 + wd + tn * 16 + col;           // B-side col
                Mp[(size_t)v * DD + d] = acc[tm][tn][r];
            }
}

// ---------------------------------------------------------------------------
// Kernel 2: pure streaming reduce -- partials are already [v][d]. Sum 4
// slices, scale by 1/sqrt(512), split bf16 hi/lo, write Mth/Mtl [b][v][d].
// 40 MB traffic, fully coalesced, no LDS, no barriers.  (round-3 form)
// ---------------------------------------------------------------------------
__global__ __launch_bounds__(256) void reduce_cvt(const float* __restrict__ Mpart,
                                                  unsigned short* __restrict__ Mth,
                                                  unsigned short* __restrict__ Mtl) {
    const size_t N  = (size_t)BATCH * DD * DV;                    // floats per slice
    const size_t i4 = ((size_t)blockIdx.x * 256 + threadIdx.x) * 4;

    float sx = 0.f, sy = 0.f, sz = 0.f, sw = 0.f;
#pragma unroll
    for (int sl = 0; sl < 4; ++sl) {
        const float4 f = *(const float4*)&Mpart[sl * N + i4];
        sx += f.x; sy += f.y; sz += f.z; sw += f.w;
    }

    const float s = 0.04419417382415922f;  // 1/sqrt(512)
    const float m0 = sx * s, m1 = sy * s, m2 = sz * s, m3 = sw * s;
    const unsigned int h0 = pk_bf16(m0, m1);
    const unsigned int h1 = pk_bf16(m2, m3);
    const float r0 = m0 - from_hi(h0 << 16);
    const float r1 = m1 - from_hi(h0 & 0xFFFF0000u);
    const float r2 = m2 - from_hi(h1 << 16);
    const float r3 = m3 - from_hi(h1 & 0xFFFF0000u);
    *(uint2*)&Mth[i4] = make_uint2(h0, h1);
    *(uint2*)&Mtl[i4] = make_uint2(pk_bf16(r0, r1), pk_bf16(r2, r3));
}

// ---------------------------------------------------------------------------
// Kernel 3: X[b] = Q[b] @ M[b] via 3-term split MFMA. B pre-split bf16
// k-contiguous from ws; Q converted on the fly. 128x128 tiles, BK=32,
// register-prefetch pipeline. (round-0 known-good form, verbatim)
// ---------------------------------------------------------------------------
__global__ __launch_bounds__(256) void qm_mfma(const float* __restrict__ Qp,
                                               const unsigned short* __restrict__ Mth,
                                               const unsigned short* __restrict__ Mtl,
                                               float* __restrict__ Xp) {
    const int b  = blockIdx.z;
    const int q0 = blockIdx.x * 128;
    const int v0 = blockIdx.y * 128;
    const float* Qb = Qp + (size_t)b * SQ * DD;
    const unsigned short* Bhg = Mth + (size_t)b * DV * DD;
    const unsigned short* Blg = Mtl + (size_t)b * DV * DD;

    __shared__ __align__(16) unsigned short Qh[128 * RP], Ql[128 * RP],
                                            Bh[128 * RP], Bl[128 * RP];

    const int tid  = threadIdx.x;
    const int lane = tid & 63;
    const int w    = tid >> 6;
    const int wq   = (w & 1) * 64;
    const int wv   = (w >> 1) * 64;

    f32x4_t acc[4][4];
#pragma unroll
    for (int i = 0; i < 4; ++i)
#pragma unroll
        for (int j = 0; j < 4; ++j) acc[i][j] = (f32x4_t){0.f, 0.f, 0.f, 0.f};

    // prefetch registers
    float4 pq[4];
    bf16x8_t pbh[2], pbl[2];
    const int qrow = tid >> 3;          // 0..31
    const int qdc  = (tid & 7) * 4;     // 0..28
    const int brow = tid >> 2;          // 0..63
    const int bkq  = tid & 3;           // 0..3
    auto load_tile = [&](int k0l) {
#pragma unroll
        for (int p = 0; p < 4; ++p)
            pq[p] = *(const float4*)&Qb[(size_t)(q0 + p * 32 + qrow) * DD + k0l + qdc];
#pragma unroll
        for (int p = 0; p < 2; ++p) {
            const size_t go = (size_t)(v0 + p * 64 + brow) * DD + k0l + bkq * 8;
            pbh[p] = *(const bf16x8_t*)&Bhg[go];
            pbl[p] = *(const bf16x8_t*)&Blg[go];
        }
    };

    load_tile(0);
    for (int k0 = 0; k0 < DD; k0 += 32) {
        // ---- stage Q (cvt+split) and B (straight copy) from regs ----
#pragma unroll
        for (int p = 0; p < 4; ++p) {
            const float4 f = pq[p];
            const unsigned int h01 = pk_bf16(f.x, f.y);
            const unsigned int h23 = pk_bf16(f.z, f.w);
            const float r0 = f.x - from_hi(h01 << 16);
            const float r1 = f.y - from_hi(h01 & 0xFFFF0000u);
            const float r2 = f.z - from_hi(h23 << 16);
            const float r3 = f.w - from_hi(h23 & 0xFFFF0000u);
            const int off = (p * 32 + qrow) * RP + qdc;
            *(uint2*)(Qh + off) = make_uint2(h01, h23);
            *(uint2*)(Ql + off) = make_uint2(pk_bf16(r0, r1), pk_bf16(r2, r3));
        }
#pragma unroll
        for (int p = 0; p < 2; ++p) {
            const int off = (p * 64 + brow) * RP + bkq * 8;
            *(bf16x8_t*)(Bh + off) = pbh[p];
            *(bf16x8_t*)(Bl + off) = pbl[p];
        }
        __syncthreads();

        if (k0 + 32 < DD) load_tile(k0 + 32);

        const int kq = lane >> 4;
        const int mr = lane & 15;
        bf16x8_t ah[4], al_[4];
#pragma unroll
        for (int tm = 0; tm < 4; ++tm) {
            const int off = (wq + tm * 16 + mr) * RP + kq * 8;
            ah[tm]  = *(const bf16x8_t*)(Qh + off);
            al_[tm] = *(const bf16x8_t*)(Ql + off);
        }
#pragma unroll
        for (int tn = 0; tn < 4; ++tn) {
            const int off = (wv + tn * 16 + mr) * RP + kq * 8;
            const bf16x8_t bh = *(const bf16x8_t*)(Bh + off);
            const bf16x8_t bl = *(const bf16x8_t*)(Bl + off);
#pragma unroll
            for (int tm = 0; tm < 4; ++tm) {
                acc[tm][tn] = __builtin_amdgcn_mfma_f32_16x16x32_bf16(ah[tm], bh, acc[tm][tn], 0, 0, 0);
                acc[tm][tn] = __builtin_amdgcn_mfma_f32_16x16x32_bf16(ah[tm], bl, acc[tm][tn], 0, 0, 0);
                acc[tm][tn] = __builtin_amdgcn_mfma_f32_16x16x32_bf16(al_[tm], bh, acc[tm][tn], 0, 0, 0);
            }
        }
        __syncthreads();
    }

    float* Xb = Xp + (size_t)b * SQ * DV;
    const int quad = lane >> 4;
    const int col  = lane & 15;
#pragma unroll
    for (int tm = 0; tm < 4; ++tm)
#pragma unroll
        for (int tn = 0; tn < 4; ++tn)
#pragma unroll
            for (int r = 0; r < 4; ++r)
                Xb[(size_t)(q0 + wq + tm * 16 + quad * 4 + r) * DV + v0 + wv + tn * 16 + col] = acc[tm][tn][r];
}

// ---------------------------------------------------------------------------
// Kernel 4: in-place masked softmax over last dim (512). One wave per row.
// ---------------------------------------------------------------------------
__global__ __launch_bounds__(256) void softmax_kernel(float* __restrict__ X,
                                                      const int* __restrict__ vlen) {
    const int wave = threadIdx.x >> 6;
    const int lane = threadIdx.x & 63;
    const int row  = blockIdx.x * 4 + wave;
    const int q    = row & (SQ - 1);
    float* xr = X + (size_t)row * DV;
    const int vl = vlen[q];

    float v[8];
#pragma unroll
    for (int u = 0; u < 2; ++u) {
        const int j0 = u * 256 + lane * 4;
        const float4 f = *(const float4*)&xr[j0];
        v[u * 4 + 0] = (j0 + 0 > vl) ? -1.0e6f : f.x;
        v[u * 4 + 1] = (j0 + 1 > vl) ? -1.0e6f : f.y;
        v[u * 4 + 2] = (j0 + 2 > vl) ? -1.0e6f : f.z;
        v[u * 4 + 3] = (j0 + 3 > vl) ? -1.0e6f : f.w;
    }

    float m = v[0];
#pragma unroll
    for (int i = 1; i < 8; ++i) m = fmaxf(m, v[i]);
#pragma unroll
    for (int off = 32; off > 0; off >>= 1) m = fmaxf(m, __shfl_xor(m, off, 64));

    float ssum = 0.f;
#pragma unroll
    for (int i = 0; i < 8; ++i) {
        v[i] = __expf(v[i] - m);
        ssum += v[i];
    }
#pragma unroll
    for (int off = 32; off > 0; off >>= 1) ssum += __shfl_xor(ssum, off, 64);

    const float inv = 1.0f / ssum;
#pragma unroll
    for (int u = 0; u < 2; ++u) {
        const int j0 = u * 256 + lane * 4;
        float4 o;
        o.x = v[u * 4 + 0] * inv;
        o.y = v[u * 4 + 1] * inv;
        o.z = v[u * 4 + 2] * inv;
        o.w = v[u * 4 + 3] * inv;
        *(float4*)&xr[j0] = o;
    }
}

extern "C" void kernel_launch(void* const* d_in, const int* in_sizes, int n_in,
                              void* d_out, int out_size, void* d_ws, size_t ws_size,
                              hipStream_t stream) {
    const float* Kp   = (const float*)d_in[0];
    const float* Vp   = (const float*)d_in[1];
    const float* Qp   = (const float*)d_in[2];
    const int*   vlen = (const int*)d_in[3];
    float* out = (float*)d_out;

    // ws: Mt_hi (4 MB) | Mt_lo (4 MB) -- proven-safe 8 MB footprint.
    unsigned short* Mth = (unsigned short*)d_ws;
    unsigned short* Mtl = Mth + (size_t)BATCH * DD * DV;
    // fp32 partials (4 x 8 MB = 32 MB) live in d_out; overwritten by qm later.
    float* Mpart = out;

    ktv_mfma<<<dim3(4, 4, 32), 256, 0, stream>>>(Kp, Vp, Mpart);
    reduce_cvt<<<dim3(2048), 256, 0, stream>>>(Mpart, Mth, Mtl);
    qm_mfma<<<dim3(16, 4, 8), 256, 0, stream>>>(Qp, Mth, Mtl, out);
    softmax_kernel<<<dim3(BATCH * SQ / 4), 256, 0, stream>>>(out, vlen);
}